// Round 1
// 12574.898 us; speedup vs baseline: 1.5514x; 1.5514x over previous
//
#include <hip/hip_runtime.h>
#include <stdint.h>

#define BB 32      // batch
#define TT 2048    // timesteps
#define DD 512     // input dim
#define HH 512     // hidden
#define NG 2048    // 4*H gate columns (interleaved: col = hid*4 + gate)

typedef short bf16x8 __attribute__((ext_vector_type(8)));
typedef float f32x4  __attribute__((ext_vector_type(4)));
typedef unsigned long long u64;

__device__ __forceinline__ unsigned short f2bf(float f) {
    union { float f; uint32_t u; } v; v.f = f;
    uint32_t u = v.u;
    return (unsigned short)((u + 0x7fffu + ((u >> 16) & 1u)) >> 16);
}
__device__ __forceinline__ float fast_tanh(float x) {
    float ax = fabsf(x);
    float e = __expf(2.0f * ax);
    float t = 1.0f - 2.0f / (e + 1.0f);
    return copysignf(t, x);
}
__device__ __forceinline__ float fast_sig(float x) {
    return 1.0f / (1.0f + __expf(-x));
}

// ---------------- prep kernels ----------------
__global__ void k_convert_x(const float* __restrict__ X, unsigned short* __restrict__ Xb) {
    int i = (blockIdx.x * 256 + threadIdx.x) * 4;
    float4 v = *(const float4*)(X + i);
    ushort4 o;
    o.x = f2bf(v.x); o.y = f2bf(v.y); o.z = f2bf(v.z); o.w = f2bf(v.w);
    *(ushort4*)(Xb + i) = o;
}

// WpT[n][k] = Wp[k][n]  (512x512)
__global__ void k_prep_wp(const float* __restrict__ Wp, unsigned short* __restrict__ WpT) {
    int idx = blockIdx.x * 256 + threadIdx.x;
    int n = idx >> 9, k = idx & 511;
    WpT[idx] = f2bf(Wp[k * HH + n]);
}

// WtopT[col][k] = Wg[k][hid], UT[col][k] = Wg[H+k][hid]; col = hid*4+g
__global__ void k_prep_u(const float* __restrict__ Wf, const float* __restrict__ Wi,
                         const float* __restrict__ Wc, const float* __restrict__ Wo,
                         const float* __restrict__ bf_, const float* __restrict__ bi_,
                         const float* __restrict__ bc_, const float* __restrict__ bo_,
                         unsigned short* __restrict__ WtopT, unsigned short* __restrict__ UT,
                         float* __restrict__ biascat) {
    int idx = blockIdx.x * 256 + threadIdx.x;   // over NG*512
    int col = idx >> 9, k = idx & 511;
    int g = col & 3, hid = col >> 2;
    const float* W = (g == 0) ? Wf : (g == 1) ? Wi : (g == 2) ? Wc : Wo;
    WtopT[idx] = f2bf(W[k * HH + hid]);
    UT[idx]    = f2bf(W[(HH + k) * HH + hid]);
    if (k == 0) {
        const float* bp = (g == 0) ? bf_ : (g == 1) ? bi_ : (g == 2) ? bc_ : bo_;
        biascat[col] = bp[hid];
    }
}

__global__ void k_zero(unsigned short* __restrict__ hbuf, int* __restrict__ flags) {
    int i = blockIdx.x * 256 + threadIdx.x;   // 128 blocks * 256 = 32768 = 2*BB*HH
    hbuf[i] = 0;
    if (i < 64) flags[i] = 0;
}

// ---------------- phase A: proj = tanh(X @ Wp + bp), stored FRAGMENT-major bf16 ----------------
// projF layout: [t][frag 0..31][lane 0..63][8 bf16], frag = half*16 + kf,
// element = proj[batch = half*16 + ln][h = kf*32 + q*8 + e], lane = q*16 + ln.
// One frag = 1 KB contiguous per wave-load in the scan.
__global__ __launch_bounds__(256)
void k_gemm_a1(const unsigned short* __restrict__ A, const unsigned short* __restrict__ BT,
               const float* __restrict__ bias, unsigned short* __restrict__ projF,
               int M, int N, int K) {
    __shared__ unsigned short lA[128 * 32];
    __shared__ unsigned short lB[128 * 32];
    const int tid  = threadIdx.x;
    const int wave = tid >> 6, lane = tid & 63;
    const int q = lane >> 4, ln = lane & 15;
    const int tm = blockIdx.x * 128, tn = blockIdx.y * 128;
    const int mtb = (wave >> 1) * 64, ntb = (wave & 1) * 64;
    f32x4 acc[4][4] = {};

    for (int kc = 0; kc < K; kc += 32) {
        __syncthreads();
        #pragma unroll
        for (int r = 0; r < 2; ++r) {
            int row = r * 64 + wave * 16 + (lane >> 2);
            const unsigned short* ga = A  + (size_t)(tm + row) * K + kc + (lane & 3) * 8;
            const unsigned short* gb = BT + (size_t)(tn + row) * K + kc + (lane & 3) * 8;
            __builtin_amdgcn_global_load_lds(
                (const __attribute__((address_space(1))) uint32_t*)ga,
                (__attribute__((address_space(3))) uint32_t*)&lA[(r * 64 + wave * 16) * 32],
                16, 0, 0);
            __builtin_amdgcn_global_load_lds(
                (const __attribute__((address_space(1))) uint32_t*)gb,
                (__attribute__((address_space(3))) uint32_t*)&lB[(r * 64 + wave * 16) * 32],
                16, 0, 0);
        }
        __syncthreads();
        bf16x8 af[4], bfr[4];
        #pragma unroll
        for (int i = 0; i < 4; ++i) {
            af[i]  = *(const bf16x8*)&lA[(mtb + i * 16 + ln) * 32 + q * 8];
            bfr[i] = *(const bf16x8*)&lB[(ntb + i * 16 + ln) * 32 + q * 8];
        }
        #pragma unroll
        for (int mi = 0; mi < 4; ++mi)
            #pragma unroll
            for (int ni = 0; ni < 4; ++ni)
                acc[mi][ni] = __builtin_amdgcn_mfma_f32_16x16x32_bf16(af[mi], bfr[ni], acc[mi][ni], 0, 0, 0);
    }

    #pragma unroll
    for (int ni = 0; ni < 4; ++ni) {
        int col = tn + ntb + ni * 16 + ln;        // hidden index 0..511
        float bz = bias[col];
        int kf = col >> 5, qv = (col >> 3) & 3, e = col & 7;
        #pragma unroll
        for (int mi = 0; mi < 4; ++mi) {
            #pragma unroll
            for (int r = 0; r < 4; ++r) {
                int row = tm + mtb + mi * 16 + q * 4 + r;  // = b*T + t
                int b = row >> 11, t = row & (TT - 1);
                float v = acc[mi][ni][r] + bz;
                size_t u16idx = (size_t)t * 16384
                              + (size_t)(((b >> 4) * 16 + kf) * 512)
                              + (size_t)((qv * 16 + (b & 15)) * 8) + e;
                projF[u16idx] = f2bf(fast_tanh(v));
            }
        }
    }
}

// ---------------- phase B: persistent recurrent kernel ----------------
// 16 blocks x 512 threads (8 waves). Block nb owns gate cols [nb*128,+128) = hidden [nb*32,+32) x 4 gates.
// Changes vs previous version (all latency-chain attacks):
//   * sync radius 64 -> 16: one flag cache line, fewer stragglers per step.
//   * h exchange: block stages the full 32KB h buffer into LDS ONCE per step via fully-coalesced
//     contiguous u64 LLC-bypass loads (8 per thread), then all 8 waves read A-fragments from LDS
//     with an XOR swizzle (byte ^ ((row&7)<<4)) to kill the 16-way ds_read_b128 bank conflict.
//     LLC h-traffic/step: 4MB -> 512KB; scattered half-line requests -> full-line requests.
//   * proj reads: fragment-major projF layout -> each proj A-frag load is 1KB contiguous per wave
//     (L1-cacheable, issued before the spin so latency hides under the wait).
// Coherence protocol unchanged: relaxed agent-scope atomics (sc0 sc1 write-through/bypass),
// producer orders h-stores before flag via the __syncthreads vmcnt drain, consumers order via the
// control dependency on the flag spin + LLC-bypass loads.
__global__ __launch_bounds__(512, 1)
void k_lstm_seq(const unsigned short* __restrict__ projF,  // [T][32 frags][64 lanes][8] bf16
                const unsigned short* __restrict__ WtopT,  // [NG][512] bf16
                const unsigned short* __restrict__ UT,     // [NG][512] bf16
                const float* __restrict__ biascat,         // [NG]
                unsigned short* __restrict__ hbuf,         // [2][B*H] bf16 (linear [b][h])
                int* __restrict__ flags,                   // [16]
                float* __restrict__ out) {                 // [B][T][H] fp32
    const int nb   = blockIdx.x;           // 0..15
    const int tid  = threadIdx.x;          // 0..511
    const int wv   = tid >> 6;             // wave 0..7
    const int lane = tid & 63;
    const int q = lane >> 4, ln = lane & 15;

    __shared__ __align__(16) unsigned short lh[16384];  // 32KB staged h, XOR-swizzled
    __shared__ float preact[32][132];                   // [batch][local gate col], stride 132 (2-way max)

    // One-time: load 16 K-frags of Wtop and U for this lane's column (resident in regs).
    const size_t colg = (size_t)(nb * 128 + wv * 16 + ln);
    bf16x8 ufrag[16], wtfrag[16];
    #pragma unroll
    for (int kf = 0; kf < 16; ++kf) {
        ufrag[kf]  = *(const bf16x8*)(UT    + colg * 512 + kf * 32 + q * 8);
        wtfrag[kf] = *(const bf16x8*)(WtopT + colg * 512 + kf * 32 + q * 8);
    }
    const float bias_lane = biascat[colg];

    // Each thread owns 2 (batch, hidden-local) cells' c-state.
    const int idx0 = tid * 2;
    const int b0 = idx0 >> 5, hl0 = idx0 & 31;   // hl0 in {0,2,...,30}; pair is hl0+1
    float c0 = 0.f, c1 = 0.f;

    // Swizzled LDS fragment-read bases: linear byte = half*16384 + ln*1024 + kf*64 + q*16,
    // row = byte>>10 = half*16+ln, XOR = (ln&7)<<4 (same for both halves).
    const int fb0 = ln * 1024 + q * 16;
    const int fx  = (ln & 7) << 4;

    for (int t = 0; t < TT; ++t) {
        const int rb = (t & 1) ^ 1, wb = t & 1;

        // ---- proj_t @ Wtop: fragment-major, 1KB-contiguous wave loads, issued pre-spin ----
        f32x4 acc0 = {}, acc1 = {};
        {
            const unsigned short* pf = projF + (size_t)t * 16384;
            #pragma unroll
            for (int kf = 0; kf < 16; ++kf) {
                bf16x8 a0 = *(const bf16x8*)(pf + kf * 512 + lane * 8);          // batches 0-15
                bf16x8 a1 = *(const bf16x8*)(pf + (16 + kf) * 512 + lane * 8);   // batches 16-31
                acc0 = __builtin_amdgcn_mfma_f32_16x16x32_bf16(a0, wtfrag[kf], acc0, 0, 0, 0);
                acc1 = __builtin_amdgcn_mfma_f32_16x16x32_bf16(a1, wtfrag[kf], acc1, 0, 0, 0);
            }
        }

        // ---- spin until all 16 blocks published h_{t-1} (one flag line, broadcast load) ----
        if (t > 0) {
            int v;
            do {
                v = __hip_atomic_load(&flags[lane & 15], __ATOMIC_RELAXED, __HIP_MEMORY_SCOPE_AGENT);
            } while (!__all(v >= t));
        }

        // ---- stage full h_{t-1} (32KB) into LDS: coalesced LLC-bypass loads, swizzled writes ----
        {
            const u64* hb = (const u64*)hbuf + (size_t)rb * 4096;
            u64 tmp[8];
            #pragma unroll
            for (int r = 0; r < 8; ++r)
                tmp[r] = __hip_atomic_load(hb + r * 512 + tid, __ATOMIC_RELAXED, __HIP_MEMORY_SCOPE_AGENT);
            #pragma unroll
            for (int r = 0; r < 8; ++r) {
                int b = (r * 512 + tid) * 8;                 // linear byte in [0,32768)
                int sw = b ^ (((b >> 10) & 7) << 4);         // row-XOR swizzle (row const per wave: conflict-free)
                *(u64*)((char*)lh + sw) = tmp[r];
            }
        }
        __syncthreads();

        // ---- h_{t-1} @ U from LDS (swizzled ds_read_b128, ~2-way max) ----
        #pragma unroll
        for (int kf = 0; kf < 16; ++kf) {
            bf16x8 a0 = *(const bf16x8*)((const char*)lh + ((fb0 + kf * 64) ^ fx));
            bf16x8 a1 = *(const bf16x8*)((const char*)lh + ((16384 + fb0 + kf * 64) ^ fx));
            acc0 = __builtin_amdgcn_mfma_f32_16x16x32_bf16(a0, ufrag[kf], acc0, 0, 0, 0);
            acc1 = __builtin_amdgcn_mfma_f32_16x16x32_bf16(a1, ufrag[kf], acc1, 0, 0, 0);
        }

        #pragma unroll
        for (int r = 0; r < 4; ++r) {
            preact[q * 4 + r][wv * 16 + ln]      = acc0[r] + bias_lane;
            preact[16 + q * 4 + r][wv * 16 + ln] = acc1[r] + bias_lane;
        }
        __syncthreads();

        // ---- gates for the 2 owned (b, hid) cells ----
        const float* pa0 = &preact[b0][hl0 * 4];
        const float* pa1 = &preact[b0][hl0 * 4 + 4];
        float f0 = fast_sig(pa0[0]);
        float i0 = fast_sig(pa0[1]);
        float g0 = fast_tanh(pa0[2]);
        float o0 = fast_sig(pa0[3]);
        c0 = f0 * c0 + i0 * g0;
        float h0 = o0 * fast_tanh(c0);

        float f1 = fast_sig(pa1[0]);
        float i1 = fast_sig(pa1[1]);
        float g1 = fast_tanh(pa1[2]);
        float o1 = fast_sig(pa1[3]);
        c1 = f1 * c1 + i1 * g1;
        float h1 = o1 * fast_tanh(c1);

        // ---- h exchange: relaxed write-through store (LLC-visible once vmcnt retires) ----
        uint32_t packed = (uint32_t)f2bf(h0) | ((uint32_t)f2bf(h1) << 16);
        __hip_atomic_store((uint32_t*)&hbuf[(size_t)wb * 16384 + b0 * 512 + nb * 32 + hl0],
                           packed, __ATOMIC_RELAXED, __HIP_MEMORY_SCOPE_AGENT);

        __syncthreads();   // barrier drain (vmcnt 0): h stores LLC-visible; preact reads done
        if (tid == 0)
            __hip_atomic_store(&flags[nb], t + 1, __ATOMIC_RELAXED, __HIP_MEMORY_SCOPE_AGENT);

        // ---- output store AFTER publish: off the inter-block critical path ----
        float2 ho; ho.x = h0; ho.y = h1;
        *(float2*)&out[((size_t)b0 * TT + t) * HH + nb * 32 + hl0] = ho;
    }
}

// ---------------- launcher ----------------
extern "C" void kernel_launch(void* const* d_in, const int* in_sizes, int n_in,
                              void* d_out, int out_size, void* d_ws, size_t ws_size,
                              hipStream_t stream) {
    const float* X   = (const float*)d_in[0];
    const float* Wp  = (const float*)d_in[1];
    const float* bp  = (const float*)d_in[2];
    const float* Wf  = (const float*)d_in[3];
    const float* bf_ = (const float*)d_in[4];
    const float* Wi  = (const float*)d_in[5];
    const float* bi_ = (const float*)d_in[6];
    const float* Wc  = (const float*)d_in[7];
    const float* bc_ = (const float*)d_in[8];
    const float* Wo  = (const float*)d_in[9];
    const float* bo_ = (const float*)d_in[10];
    float* out = (float*)d_out;

    char* w = (char*)d_ws;
    auto alloc = [&](size_t bytes) {
        char* p = w;
        w += (bytes + 255) & ~(size_t)255;
        return p;
    };
    unsigned short* projF  = (unsigned short*)alloc((size_t)BB * TT * HH * 2); // 64 MB fragment-major
    unsigned short* WpT    = (unsigned short*)alloc((size_t)DD * HH * 2);      // 0.5 MB
    unsigned short* WtopT  = (unsigned short*)alloc((size_t)NG * HH * 2);      // 2 MB
    unsigned short* UT     = (unsigned short*)alloc((size_t)NG * HH * 2);      // 2 MB
    float*          biascat= (float*)alloc(NG * 4);
    unsigned short* hbuf   = (unsigned short*)alloc(2 * BB * HH * 2);
    int*            flags  = (int*)alloc(1024);

    // Xb (bf16 X, 64 MB) borrows d_out (128 MB): consumed by k_gemm_a1 before phase B writes out.
    unsigned short* Xb = (unsigned short*)d_out;

    k_convert_x<<<(BB * TT * DD) / (256 * 4), 256, 0, stream>>>(X, Xb);
    k_prep_wp<<<(DD * HH) / 256, 256, 0, stream>>>(Wp, WpT);
    k_prep_u<<<(NG * HH) / 256, 256, 0, stream>>>(Wf, Wi, Wc, Wo, bf_, bi_, bc_, bo_,
                                                  WtopT, UT, biascat);
    k_zero<<<128, 256, 0, stream>>>(hbuf, flags);

    // proj fragment-major = tanh(X @ Wp + bp)
    k_gemm_a1<<<dim3((BB * TT) / 128, HH / 128), 256, 0, stream>>>(Xb, WpT, bp, projF,
                                                                   BB * TT, HH, DD);
    // sequential scan: 16 blocks x 512 threads, radius-16 sync, LDS-staged h exchange
    k_lstm_seq<<<16, 512, 0, stream>>>(projF, WtopT, UT, biascat, hbuf, flags, out);
}